// Round 1
// baseline (235.327 us; speedup 1.0000x reference)
//
#include <hip/hip_runtime.h>

// BLAMem: truncated tensor-algebra (depth 4, C=8) log-signature memory.
// Key identity: BCH-prefix-scan of chunk log-sigs == ta_log of ta_mul-prefix-scan
// of chunk signatures (exp/log are exact inverses in the nilpotent truncated algebra).

#define MEM   4680   // 8 + 64 + 512 + 4096
#define OFF2  8
#define OFF3  72
#define OFF4  584
#define NCH   128
#define TLEN  2048

// ---------------------------------------------------------------- chunk sigs
__global__ __launch_bounds__(256) void chunk_sig_kernel(const float* __restrict__ x,
                                                        float* __restrict__ out) {
    int blk = blockIdx.x;
    int b = blk >> 7, n = blk & 127;
    int tid = threadIdx.x;
    int lane = tid & 63, w = tid >> 6;
    int kq = lane >> 3, lq = lane & 7;

    __shared__ float sInc[16 * 8];
    __shared__ float sL1[8], sL2[64], sL3[512];

    if (tid < 128) {
        int s = tid >> 3, c = tid & 7;
        int t = n * 16 + s;
        float v;
        if (c < 7) {
            float cur  = x[(b * TLEN + t) * 7 + c];
            float prev = (t > 0) ? x[(b * TLEN + t - 1) * 7 + c] : 0.0f;
            v = cur - prev;
        } else {
            v = (t > 0) ? ((float)t * (1.0f / 2047.0f) - (float)(t - 1) * (1.0f / 2047.0f))
                        : 0.0f;
        }
        sInc[s * 8 + c] = v;
    }
    if (tid < 8)  sL1[tid] = 0.0f;
    if (tid < 64) sL2[tid] = 0.0f;
    sL3[tid] = 0.0f;
    sL3[tid + 256] = 0.0f;

    float c4[16];
#pragma unroll
    for (int r = 0; r < 16; r++) c4[r] = 0.0f;
    __syncthreads();

    for (int s = 0; s < 16; s++) {
        const float* d = &sInc[s * 8];
        float dk = d[kq], dl = d[lq];

        // level-4 accumulate (registers): r4 += d[l]*(c3[ijk] + d[k]*(c2[ij]/2 + d[j]*(c1[i]/6 + d[i]/24)))
#pragma unroll
        for (int r = 0; r < 16; r++) {
            int row = w + 4 * r;
            int i = row >> 3, j = row & 7;
            float a1 = sL1[i], a2 = sL2[row];
            float c3v = sL3[row * 8 + kq];
            float coef = c3v + dk * (a2 * 0.5f + d[j] * (a1 * (1.0f / 6.0f) + d[i] * (1.0f / 24.0f)));
            c4[r] += coef * dl;
        }
        // level-3: new3 = c3 + d[k]*(c2[ij] + d[j]*(c1[i]/2 + d[i]/6))   (here j=kq, k=lq)
        float n3[2];
#pragma unroll
        for (int r2 = 0; r2 < 2; r2++) {
            int m3 = tid + 256 * r2;
            int i3 = w + 4 * r2;
            n3[r2] = sL3[m3] + dl * (sL2[i3 * 8 + kq] + dk * (sL1[i3] * 0.5f + d[i3] * (1.0f / 6.0f)));
        }
        float n2 = 0.0f, n1 = 0.0f;
        if (tid < 64) n2 = sL2[tid] + sL1[tid >> 3] * d[tid & 7] + d[tid >> 3] * d[tid & 7] * 0.5f;
        if (tid < 8)  n1 = sL1[tid] + d[tid];
        __syncthreads();
        sL3[tid] = n3[0];
        sL3[tid + 256] = n3[1];
        if (tid < 64) sL2[tid] = n2;
        if (tid < 8)  sL1[tid] = n1;
        __syncthreads();
    }

    size_t base = (size_t)blk * MEM;
#pragma unroll
    for (int r = 0; r < 16; r++) {
        int row = w + 4 * r;
        out[base + OFF4 + row * 64 + lane] = c4[r];
    }
    out[base + OFF3 + tid] = sL3[tid];
    out[base + OFF3 + 256 + tid] = sL3[tid + 256];
    if (tid < 64) out[base + OFF2 + tid] = sL2[tid];
    if (tid < 8)  out[base + tid] = sL1[tid];
}

// ---------------------------------------------------------------- scan round
// out[b,n] = (n>=d) ? ta_mul(in[b,n-d], in[b,n]) : in[b,n]
__global__ __launch_bounds__(256) void scan_round_kernel(const float* __restrict__ in,
                                                         float* __restrict__ out, int d) {
    int blk = blockIdx.x;
    int n = blk & 127;
    int tid = threadIdx.x;
    size_t baseB = (size_t)blk * MEM;

    if (n < d) {
        const float4* src = (const float4*)(in + baseB);
        float4* dst = (float4*)(out + baseB);
        for (int m = tid; m < MEM / 4; m += 256) dst[m] = src[m];
        return;
    }

    __shared__ float sA[MEM], sB[MEM];
    size_t baseA = (size_t)(blk - d) * MEM;
    {
        const float4* srcA = (const float4*)(in + baseA);
        const float4* srcB = (const float4*)(in + baseB);
        float4* dA = (float4*)sA;
        float4* dB = (float4*)sB;
        for (int m = tid; m < MEM / 4; m += 256) {
            dA[m] = srcA[m];
            dB[m] = srcB[m];
        }
    }
    __syncthreads();

    int lane = tid & 63, w = tid >> 6;
    int kq = lane >> 3, lq = lane & 7;
    float b1l = sB[lq];
    float b2lane = sB[OFF2 + lane];

    // r4[ijkl] = a4+b4 + a1[i]*b3[jkl] + a2[ij]*b2[kl] + a3[ijk]*b1[l]
#pragma unroll
    for (int r = 0; r < 16; r++) {
        int row = w + 4 * r;
        int i = row >> 3, j = row & 7;
        int m = row * 64 + lane;
        float v = sA[OFF4 + m] + sB[OFF4 + m]
                + sA[i] * sB[OFF3 + j * 64 + lane]
                + sA[OFF2 + row] * b2lane
                + sA[OFF3 + row * 8 + kq] * b1l;
        out[baseB + OFF4 + m] = v;
    }
    // r3[ijk] = a3+b3 + a1[i]*b2[jk] + a2[ij]*b1[k]
#pragma unroll
    for (int r2 = 0; r2 < 2; r2++) {
        int m3 = tid + 256 * r2;
        int i3 = w + 4 * r2;
        float v = sA[OFF3 + m3] + sB[OFF3 + m3]
                + sA[i3] * b2lane
                + sA[OFF2 + i3 * 8 + kq] * b1l;
        out[baseB + OFF3 + m3] = v;
    }
    if (tid < 64) out[baseB + OFF2 + tid] = sA[OFF2 + tid] + sB[OFF2 + tid] + sA[tid >> 3] * sB[tid & 7];
    if (tid < 8)  out[baseB + tid] = sA[tid] + sB[tid];
}

// ---------------------------------------------------------------- ta_log
// out = s - s^2/2 + s^3/3 - s^4/4 under ta_mulz
__global__ __launch_bounds__(256) void talog_kernel(const float* __restrict__ in,
                                                    float* __restrict__ out) {
    int blk = blockIdx.x;
    int tid = threadIdx.x;
    size_t base = (size_t)blk * MEM;
    __shared__ float sS[MEM];
    __shared__ float sP22[64], sP23[512];
    {
        const float4* src = (const float4*)(in + base);
        float4* dst = (float4*)sS;
        for (int m = tid; m < MEM / 4; m += 256) dst[m] = src[m];
    }
    __syncthreads();

    int lane = tid & 63, w = tid >> 6;
    int kq = lane >> 3, lq = lane & 7;

    if (tid < 64) sP22[tid] = sS[tid >> 3] * sS[tid & 7];
#pragma unroll
    for (int r2 = 0; r2 < 2; r2++) {
        int m3 = tid + 256 * r2;
        int i3 = w + 4 * r2;
        // p2_3[ijk] = s1[i]*s2[jk] + s2[ij]*s1[k]
        sP23[m3] = sS[i3] * sS[OFF2 + lane] + sS[OFF2 + i3 * 8 + kq] * sS[lq];
    }
    __syncthreads();

    float s1l = sS[lq];
    float s2lane = sS[OFF2 + lane];
    float p22lane = sP22[lane];
#pragma unroll
    for (int r = 0; r < 16; r++) {
        int row = w + 4 * r;
        int i = row >> 3, j = row & 7;
        int m = row * 64 + lane;
        float s1i = sS[i];
        float p24 = s1i * sS[OFF3 + j * 64 + lane] + sS[OFF2 + row] * s2lane + sS[OFF3 + row * 8 + kq] * s1l;
        float p34 = s1i * sP23[j * 64 + lane] + sS[OFF2 + row] * p22lane;
        float p44 = s1i * sS[j] * p22lane;
        out[base + OFF4 + m] = sS[OFF4 + m] - 0.5f * p24 + (1.0f / 3.0f) * p34 - 0.25f * p44;
    }
#pragma unroll
    for (int r2 = 0; r2 < 2; r2++) {
        int m3 = tid + 256 * r2;
        int i3 = w + 4 * r2;
        out[base + OFF3 + m3] = sS[OFF3 + m3] - 0.5f * sP23[m3] + (1.0f / 3.0f) * sS[i3] * p22lane;
    }
    if (tid < 64) out[base + OFF2 + tid] = sS[OFF2 + tid] - 0.5f * sP22[tid];
    if (tid < 8)  out[base + tid] = sS[tid];
}

// ---------------------------------------------------------------- pool + MLP
__global__ __launch_bounds__(256) void pool_kernel(const float* __restrict__ logbuf,
                                                   float* __restrict__ pooled) {
    int bx = blockIdx.x;
    int b = bx / 19, cc = bx % 19;
    int idx = cc * 256 + threadIdx.x;
    if (idx >= MEM) return;
    float acc = 0.0f;
    const float* p = logbuf + (size_t)b * NCH * MEM + idx;
    for (int n = 0; n < NCH; n++) acc += p[(size_t)n * MEM];
    pooled[b * MEM + idx] = acc * (1.0f / NCH);
}

__global__ __launch_bounds__(256) void zero_kernel(float* __restrict__ hbuf) {
    hbuf[blockIdx.x * 256 + threadIdx.x] = 0.0f;
}

__global__ __launch_bounds__(256) void gemv1_kernel(const float* __restrict__ pooled,
                                                    const float* __restrict__ W1,
                                                    float* __restrict__ hbuf) {
    int bx = blockIdx.x;
    int b = bx / 19, kc = bx % 19;
    int tid = threadIdx.x;
    int k0 = kc * 256;
    int k1 = (k0 + 256 < MEM) ? (k0 + 256) : MEM;
    float acc = 0.0f;
    for (int k = k0; k < k1; k++)
        acc += pooled[b * MEM + k] * W1[(size_t)k * 256 + tid];
    atomicAdd(&hbuf[b * 256 + tid], acc);
}

__global__ __launch_bounds__(256) void final_kernel(const float* __restrict__ hbuf,
                                                    const float* __restrict__ b1,
                                                    const float* __restrict__ W2,
                                                    const float* __restrict__ b2,
                                                    float* __restrict__ outp) {
    int b = blockIdx.x;
    int tid = threadIdx.x;
    float v = hbuf[b * 256 + tid] + b1[tid];
    v = fmaxf(v, 0.0f) * W2[tid];
    __shared__ float sRed[256];
    sRed[tid] = v;
    __syncthreads();
    for (int s = 128; s > 0; s >>= 1) {
        if (tid < s) sRed[tid] += sRed[tid + s];
        __syncthreads();
    }
    if (tid == 0) outp[b] = sRed[0] + b2[0];
}

// ---------------------------------------------------------------- launch
extern "C" void kernel_launch(void* const* d_in, const int* in_sizes, int n_in,
                              void* d_out, int out_size, void* d_ws, size_t ws_size,
                              hipStream_t stream) {
    const float* x  = (const float*)d_in[0];
    const float* W1 = (const float*)d_in[1];
    const float* b1 = (const float*)d_in[2];
    const float* W2 = (const float*)d_in[3];
    const float* b2 = (const float*)d_in[4];
    float* out = (float*)d_out;

    float* ws = (float*)d_ws;
    float* buf0 = ws;                              // 1024*4680 floats
    float* buf1 = ws + (size_t)1024 * MEM;         // 1024*4680 floats
    float* pooled = ws + (size_t)2048 * MEM;       // 8*4680
    float* hbuf = pooled + 8 * MEM;                // 8*256

    zero_kernel<<<8, 256, 0, stream>>>(hbuf);
    chunk_sig_kernel<<<1024, 256, 0, stream>>>(x, buf0);

    float* a = buf0;
    float* c = buf1;
    for (int d = 1; d < NCH; d <<= 1) {
        scan_round_kernel<<<1024, 256, 0, stream>>>(a, c, d);
        float* t = a; a = c; c = t;
    }
    // final scan result in a; write log into c
    talog_kernel<<<1024, 256, 0, stream>>>(a, c);
    pool_kernel<<<8 * 19, 256, 0, stream>>>(c, pooled);
    gemv1_kernel<<<8 * 19, 256, 0, stream>>>(pooled, W1, hbuf);
    final_kernel<<<8, 256, 0, stream>>>(hbuf, b1, W2, b2, out);
}

// Round 2
// 166.799 us; speedup vs baseline: 1.4108x; 1.4108x over previous
//
#include <hip/hip_runtime.h>

// BLAMem: truncated tensor-algebra (depth 4, C=8) log-signature memory.
// Identities used:
//  (1) BCH-prefix-scan of chunk log-sigs == ta_log of ta_mul-prefix-scan of chunk sigs.
//  (2) Chen: continuing the rank-1 exp(d) fold across chunk boundaries yields the
//      within-group inclusive chunk prefixes for free (snapshot every 16 steps).

#define MEM   4680   // 8 + 64 + 512 + 4096
#define OFF2  8
#define OFF3  72
#define OFF4  584
#define NCH   128
#define NG    32     // groups per batch
#define LCH   4      // chunks per group
#define GSTEPS 64    // raw steps per group
#define TLEN  2048

// ------------------------------------------------ group sigs with chunk snapshots
// block = b*NG + g. Folds 64 rank-1 exp(d) factors; snapshots accumulator at each
// chunk boundary into Q[(blk*LCH + c)*MEM ...]. Q[.. c] = local_0 (x) ... (x) local_c.
__global__ __launch_bounds__(256) void group_sig_kernel(const float* __restrict__ x,
                                                        float* __restrict__ Q) {
    int blk = blockIdx.x;
    int b = blk >> 5, g = blk & 31;
    int tid = threadIdx.x;
    int lane = tid & 63, w = tid >> 6;
    int kq = lane >> 3, lq = lane & 7;

    __shared__ float sInc[GSTEPS * 8];
    __shared__ float sL1[8], sL2[64], sL3[512];

    for (int e = tid; e < GSTEPS * 8; e += 256) {
        int s = e >> 3, c = e & 7;
        int t = g * GSTEPS + s;
        float v;
        if (c < 7) {
            float cur  = x[(b * TLEN + t) * 7 + c];
            float prev = (t > 0) ? x[(b * TLEN + t - 1) * 7 + c] : 0.0f;
            v = cur - prev;
        } else {
            v = (t > 0) ? (1.0f / 2047.0f) : 0.0f;
        }
        sInc[e] = v;
    }
    if (tid < 8)  sL1[tid] = 0.0f;
    if (tid < 64) sL2[tid] = 0.0f;
    sL3[tid] = 0.0f;
    sL3[tid + 256] = 0.0f;

    float c4[16];
#pragma unroll
    for (int r = 0; r < 16; r++) c4[r] = 0.0f;
    __syncthreads();

    for (int s = 0; s < GSTEPS; s++) {
        const float* d = &sInc[s * 8];
        float dk = d[kq], dl = d[lq];

        // L4 += d[l]*(c3[ijk] + d[k]*(c2[ij]/2 + d[j]*(c1[i]/6 + d[i]/24)))
#pragma unroll
        for (int r = 0; r < 16; r++) {
            int row = w + 4 * r;
            int i = row >> 3, j = row & 7;
            float coef = sL3[row * 8 + kq]
                       + dk * (sL2[row] * 0.5f + d[j] * (sL1[i] * (1.0f / 6.0f) + d[i] * (1.0f / 24.0f)));
            c4[r] += coef * dl;
        }
        float n3[2];
#pragma unroll
        for (int r2 = 0; r2 < 2; r2++) {
            int m3 = tid + 256 * r2;
            int i3 = w + 4 * r2;
            n3[r2] = sL3[m3] + dl * (sL2[i3 * 8 + kq] + dk * (sL1[i3] * 0.5f + d[i3] * (1.0f / 6.0f)));
        }
        float n2 = 0.0f, n1 = 0.0f;
        if (tid < 64) n2 = sL2[tid] + sL1[tid >> 3] * d[tid & 7] + d[tid >> 3] * d[tid & 7] * 0.5f;
        if (tid < 8)  n1 = sL1[tid] + d[tid];
        __syncthreads();
        sL3[tid] = n3[0];
        sL3[tid + 256] = n3[1];
        if (tid < 64) sL2[tid] = n2;
        if (tid < 8)  sL1[tid] = n1;
        __syncthreads();

        if ((s & 15) == 15) {
            int c = s >> 4;
            size_t qbase = (size_t)(blk * LCH + c) * MEM;
#pragma unroll
            for (int r = 0; r < 16; r++) {
                int row = w + 4 * r;
                Q[qbase + OFF4 + row * 64 + lane] = c4[r];
            }
            Q[qbase + OFF3 + tid] = sL3[tid];
            Q[qbase + OFF3 + 256 + tid] = sL3[tid + 256];
            if (tid < 64) Q[qbase + OFF2 + tid] = sL2[tid];
            if (tid < 8)  Q[qbase + tid] = sL1[tid];
        }
    }
}

// ------------------------------------------------ H-S scan over group products
// out[b,n] = (n>=d) ? ta_mul(in[b,n-d], in[b,n]) : in[b,n]
// input row index = blk*inMul + inAdd (lets round 1 read the c=3 slices of Q).
__global__ __launch_bounds__(256) void gp_scan_kernel(const float* __restrict__ in,
                                                      float* __restrict__ out,
                                                      int d, int inMul, int inAdd) {
    int blk = blockIdx.x;
    int n = blk & 31;
    int tid = threadIdx.x;
    size_t baseB = ((size_t)blk * inMul + inAdd) * MEM;
    size_t baseO = (size_t)blk * MEM;

    if (n < d) {
        const float4* src = (const float4*)(in + baseB);
        float4* dst = (float4*)(out + baseO);
        for (int m = tid; m < MEM / 4; m += 256) dst[m] = src[m];
        return;
    }

    __shared__ float sA[MEM], sB[MEM];
    size_t baseA = ((size_t)(blk - d) * inMul + inAdd) * MEM;
    {
        const float4* srcA = (const float4*)(in + baseA);
        const float4* srcB = (const float4*)(in + baseB);
        float4* dA = (float4*)sA;
        float4* dB = (float4*)sB;
        for (int m = tid; m < MEM / 4; m += 256) {
            dA[m] = srcA[m];
            dB[m] = srcB[m];
        }
    }
    __syncthreads();

    int lane = tid & 63, w = tid >> 6;
    int kq = lane >> 3, lq = lane & 7;
    float b1l = sB[lq];
    float b2lane = sB[OFF2 + lane];

#pragma unroll
    for (int r = 0; r < 16; r++) {
        int row = w + 4 * r;
        int i = row >> 3, j = row & 7;
        int m = row * 64 + lane;
        out[baseO + OFF4 + m] = sA[OFF4 + m] + sB[OFF4 + m]
                              + sA[i] * sB[OFF3 + j * 64 + lane]
                              + sA[OFF2 + row] * b2lane
                              + sA[OFF3 + row * 8 + kq] * b1l;
    }
#pragma unroll
    for (int r2 = 0; r2 < 2; r2++) {
        int m3 = tid + 256 * r2;
        int i3 = w + 4 * r2;
        out[baseO + OFF3 + m3] = sA[OFF3 + m3] + sB[OFF3 + m3]
                               + sA[i3] * b2lane
                               + sA[OFF2 + i3 * 8 + kq] * b1l;
    }
    if (tid < 64) out[baseO + OFF2 + tid] = sA[OFF2 + tid] + sB[OFF2 + tid] + sA[tid >> 3] * sB[tid & 7];
    if (tid < 8)  out[baseO + tid] = sA[tid] + sB[tid];
}

// ------------------------------------------------ apply group prefix + log + pool
// block = b*NG + g: for c=0..3: R = P[b][g-1] (x) Q[b][g][c]; accumulate ta_log(R).
// Writes per-(b,g) pooled partial (sum over the 4 chunks).
__global__ __launch_bounds__(256) void apply_log_pool_kernel(const float* __restrict__ Q,
                                                             const float* __restrict__ P,
                                                             float* __restrict__ partial) {
    int blk = blockIdx.x;
    int g = blk & 31;
    int tid = threadIdx.x;
    int lane = tid & 63, w = tid >> 6;
    int kq = lane >> 3, lq = lane & 7;

    __shared__ float sA[MEM];     // left operand (group prefix, or 0 = identity)
    __shared__ float sB[MEM];     // Q chunk
    __shared__ float sR[OFF4];    // R levels 1..3 (584)
    __shared__ float sP23[512];   // (R^2) level 3

    if (g == 0) {
        for (int m = tid; m < MEM; m += 256) sA[m] = 0.0f;
    } else {
        size_t basePrev = (size_t)(blk - 1) * MEM;
        const float4* src = (const float4*)(P + basePrev);
        float4* dst = (float4*)sA;
        for (int m = tid; m < MEM / 4; m += 256) dst[m] = src[m];
    }

    float pool4[16];
#pragma unroll
    for (int r = 0; r < 16; r++) pool4[r] = 0.0f;
    float pool3[2] = {0.0f, 0.0f};
    float pool2 = 0.0f, pool1 = 0.0f;

    for (int c = 0; c < LCH; c++) {
        __syncthreads();
        {
            size_t baseQ = (size_t)(blk * LCH + c) * MEM;
            const float4* src = (const float4*)(Q + baseQ);
            float4* dst = (float4*)sB;
            for (int m = tid; m < MEM / 4; m += 256) dst[m] = src[m];
        }
        __syncthreads();

        float b1l = sB[lq];
        float b2lane = sB[OFF2 + lane];

        // R levels
        float r1 = 0.0f, r2v = 0.0f;
        float r3v[2];
#pragma unroll
        for (int r2 = 0; r2 < 2; r2++) {
            int m3 = tid + 256 * r2;
            int i3 = w + 4 * r2;
            r3v[r2] = sA[OFF3 + m3] + sB[OFF3 + m3]
                    + sA[i3] * b2lane
                    + sA[OFF2 + i3 * 8 + kq] * b1l;
        }
        if (tid < 64) r2v = sA[OFF2 + tid] + sB[OFF2 + tid] + sA[tid >> 3] * sB[tid & 7];
        if (tid < 8)  r1 = sA[tid] + sB[tid];

        float r4[16];
#pragma unroll
        for (int r = 0; r < 16; r++) {
            int row = w + 4 * r;
            int i = row >> 3, j = row & 7;
            int m = row * 64 + lane;
            r4[r] = sA[OFF4 + m] + sB[OFF4 + m]
                  + sA[i] * sB[OFF3 + j * 64 + lane]
                  + sA[OFF2 + row] * b2lane
                  + sA[OFF3 + row * 8 + kq] * b1l;
        }

        // publish R low levels
#pragma unroll
        for (int r2 = 0; r2 < 2; r2++) sR[OFF3 + tid + 256 * r2] = r3v[r2];
        if (tid < 64) sR[OFF2 + tid] = r2v;
        if (tid < 8)  sR[tid] = r1;
        __syncthreads();

        // (R^2) level 3
#pragma unroll
        for (int r2 = 0; r2 < 2; r2++) {
            int m3 = tid + 256 * r2;
            int i = m3 >> 6;
            sP23[m3] = sR[i] * sR[OFF2 + (m3 & 63)]
                     + sR[OFF2 + i * 8 + ((m3 >> 3) & 7)] * sR[m3 & 7];
        }
        __syncthreads();

        // ta_log and pool
        float s1l = sR[lq];
        float s2lane = sR[OFF2 + lane];
        float p22lane = sR[kq] * sR[lq];
#pragma unroll
        for (int r = 0; r < 16; r++) {
            int row = w + 4 * r;
            int i = row >> 3, j = row & 7;
            float s1i = sR[i];
            float p24 = s1i * sR[OFF3 + j * 64 + lane] + sR[OFF2 + row] * s2lane
                      + sR[OFF3 + row * 8 + kq] * s1l;
            float p34 = s1i * sP23[j * 64 + lane] + sR[OFF2 + row] * p22lane;
            float p44 = s1i * sR[j] * p22lane;
            pool4[r] += r4[r] - 0.5f * p24 + (1.0f / 3.0f) * p34 - 0.25f * p44;
        }
#pragma unroll
        for (int r2 = 0; r2 < 2; r2++) {
            int m3 = tid + 256 * r2;
            int i3 = w + 4 * r2;
            pool3[r2] += r3v[r2] - 0.5f * sP23[m3] + (1.0f / 3.0f) * sR[i3] * p22lane;
        }
        if (tid < 64) pool2 += r2v - 0.5f * sR[tid >> 3] * sR[tid & 7];
        if (tid < 8)  pool1 += r1;
    }

    size_t baseO = (size_t)blk * MEM;
#pragma unroll
    for (int r = 0; r < 16; r++) {
        int row = w + 4 * r;
        partial[baseO + OFF4 + row * 64 + lane] = pool4[r];
    }
    partial[baseO + OFF3 + tid] = pool3[0];
    partial[baseO + OFF3 + 256 + tid] = pool3[1];
    if (tid < 64) partial[baseO + OFF2 + tid] = pool2;
    if (tid < 8)  partial[baseO + tid] = pool1;
}

// ------------------------------------------------ pool reduce over groups
__global__ __launch_bounds__(256) void pool_reduce_kernel(const float* __restrict__ partial,
                                                          float* __restrict__ pooled) {
    int bx = blockIdx.x;
    int b = bx / 19, cc = bx % 19;
    int idx = cc * 256 + threadIdx.x;
    if (idx >= MEM) return;
    float acc = 0.0f;
    const float* p = partial + (size_t)b * NG * MEM + idx;
    for (int gg = 0; gg < NG; gg++) acc += p[(size_t)gg * MEM];
    pooled[b * MEM + idx] = acc * (1.0f / NCH);
}

// ------------------------------------------------ MLP
__global__ __launch_bounds__(256) void zero_kernel(float* __restrict__ hbuf) {
    hbuf[blockIdx.x * 256 + threadIdx.x] = 0.0f;
}

// W1 read exactly once; each block handles 32 k-rows for all 8 batches.
__global__ __launch_bounds__(256) void gemv1_kernel(const float* __restrict__ pooled,
                                                    const float* __restrict__ W1,
                                                    float* __restrict__ hbuf) {
    int kc = blockIdx.x;
    int tid = threadIdx.x;
    int k0 = kc * 32;
    __shared__ float sp[8][32];
    {
        int b = tid >> 5, kk = tid & 31;
        sp[b][kk] = (k0 + kk < MEM) ? pooled[b * MEM + k0 + kk] : 0.0f;
    }
    __syncthreads();
    float acc[8];
#pragma unroll
    for (int b = 0; b < 8; b++) acc[b] = 0.0f;
    int kend = (k0 + 32 < MEM) ? (k0 + 32) : MEM;
    for (int k = k0; k < kend; k++) {
        float wv = W1[(size_t)k * 256 + tid];
#pragma unroll
        for (int b = 0; b < 8; b++) acc[b] += sp[b][k - k0] * wv;
    }
#pragma unroll
    for (int b = 0; b < 8; b++) atomicAdd(&hbuf[b * 256 + tid], acc[b]);
}

__global__ __launch_bounds__(256) void final_kernel(const float* __restrict__ hbuf,
                                                    const float* __restrict__ b1,
                                                    const float* __restrict__ W2,
                                                    const float* __restrict__ b2,
                                                    float* __restrict__ outp) {
    int b = blockIdx.x;
    int tid = threadIdx.x;
    float v = hbuf[b * 256 + tid] + b1[tid];
    v = fmaxf(v, 0.0f) * W2[tid];
    __shared__ float sRed[256];
    sRed[tid] = v;
    __syncthreads();
    for (int s = 128; s > 0; s >>= 1) {
        if (tid < s) sRed[tid] += sRed[tid + s];
        __syncthreads();
    }
    if (tid == 0) outp[b] = sRed[0] + b2[0];
}

// ------------------------------------------------ launch
extern "C" void kernel_launch(void* const* d_in, const int* in_sizes, int n_in,
                              void* d_out, int out_size, void* d_ws, size_t ws_size,
                              hipStream_t stream) {
    const float* x  = (const float*)d_in[0];
    const float* W1 = (const float*)d_in[1];
    const float* b1 = (const float*)d_in[2];
    const float* W2 = (const float*)d_in[3];
    const float* b2 = (const float*)d_in[4];
    float* out = (float*)d_out;

    float* ws = (float*)d_ws;
    float* Q       = ws;                               // 1024*MEM
    float* gpA     = Q + (size_t)1024 * MEM;           // 256*MEM
    float* gpB     = gpA + (size_t)256 * MEM;          // 256*MEM
    float* partial = gpB + (size_t)256 * MEM;          // 256*MEM
    float* pooled  = partial + (size_t)256 * MEM;      // 8*MEM
    float* hbuf    = pooled + 8 * MEM;                 // 8*256

    zero_kernel<<<8, 256, 0, stream>>>(hbuf);
    group_sig_kernel<<<256, 256, 0, stream>>>(x, Q);

    // H-S scan over 32 group products per batch. Round 1 reads the c=3 slices of Q.
    float* a = gpA;
    float* c = gpB;
    gp_scan_kernel<<<256, 256, 0, stream>>>(Q, a, 1, LCH, LCH - 1);
    for (int d = 2; d < NG; d <<= 1) {
        gp_scan_kernel<<<256, 256, 0, stream>>>(a, c, d, 1, 0);
        float* t = a; a = c; c = t;
    }
    // inclusive group prefixes now in `a`
    apply_log_pool_kernel<<<256, 256, 0, stream>>>(Q, a, partial);
    pool_reduce_kernel<<<8 * 19, 256, 0, stream>>>(partial, pooled);
    gemv1_kernel<<<147, 256, 0, stream>>>(pooled, W1, hbuf);
    final_kernel<<<8, 256, 0, stream>>>(hbuf, b1, W2, b2, out);
}